// Round 1
// baseline (309.326 us; speedup 1.0000x reference)
//
#include <hip/hip_runtime.h>

#define Kc 512
#define Dc 64
#define Hc 64
#define Bc 16
#define Tc 16384
#define Nt (Bc * Tc)              // 262144 tokens
#define LN_EPS 1e-5f
// loss = (1 + 0.25) * mean over N*D elements
#define LOSS_SCALE (1.25f / 16777216.0f)   // 1.25 / (Nt*Dc)

// ---------------------------------------------------------------------------
// Kernel 1: per-t-value table precompute. 512 blocks, 64 threads (one wave).
// Each block handles one possible t value v: encoder -> z[64] -> argmin over
// 512 codewords -> store q row / idx / d2.
// ---------------------------------------------------------------------------
__global__ __launch_bounds__(64) void precompute_kernel(
    const float* __restrict__ W1, const float* __restrict__ b1,
    const float* __restrict__ ln_g, const float* __restrict__ ln_b,
    const float* __restrict__ W2, const float* __restrict__ b2,
    const float* __restrict__ cb,
    float* __restrict__ q_table, float* __restrict__ idxf_table,
    float* __restrict__ d2_table, float* __restrict__ out_loss)
{
    const int v = blockIdx.x;       // t value, 0..511
    const int lane = threadIdx.x;   // 0..63  (= H index, = D index)

    __shared__ float s_h[Hc];
    __shared__ float s_z[Dc];

    // encoder: h = norm_t * W1 + b1
    const float norm_t = (float)v * (2.0f / (float)(Kc - 1)) - 1.0f;
    float h = norm_t * W1[lane] + b1[lane];

    // LayerNorm over H=64 == one wave: shuffle reductions
    float s = h;
    #pragma unroll
    for (int o = 32; o > 0; o >>= 1) s += __shfl_xor(s, o);
    const float mu = s * (1.0f / (float)Hc);
    const float d = h - mu;
    float vs = d * d;
    #pragma unroll
    for (int o = 32; o > 0; o >>= 1) vs += __shfl_xor(vs, o);
    const float var = vs * (1.0f / (float)Hc);
    float hn = d * rsqrtf(var + LN_EPS) * ln_g[lane] + ln_b[lane];
    hn = fmaxf(hn, 0.0f);           // relu
    s_h[lane] = hn;
    __syncthreads();

    // z[lane] = sum_h s_h[h] * W2[h][lane] + b2[lane]   (coalesced W2 reads)
    float z = b2[lane];
    #pragma unroll
    for (int hh = 0; hh < Hc; ++hh) z = fmaf(s_h[hh], W2[hh * Dc + lane], z);
    s_z[lane] = z;
    __syncthreads();

    // argmin over 512 codewords; lane handles k = kk*64 + lane (ascending)
    float best_d = 3.4e38f;
    int best_k = 0;
    for (int kk = 0; kk < Kc / 64; ++kk) {
        const int k = kk * 64 + lane;
        const float* e = cb + k * Dc;
        float dist = 0.0f;
        #pragma unroll
        for (int dd = 0; dd < Dc; ++dd) {
            const float df = s_z[dd] - e[dd];   // s_z[dd]: LDS broadcast, no conflict
            dist = fmaf(df, df, dist);
        }
        if (dist < best_d) { best_d = dist; best_k = k; }   // strict < => first index
    }
    // cross-lane argmin with first-index tie-break (lexicographic (d, k))
    #pragma unroll
    for (int o = 32; o > 0; o >>= 1) {
        const float od = __shfl_xor(best_d, o);
        const int   ok = __shfl_xor(best_k, o);
        if (od < best_d || (od == best_d && ok < best_k)) { best_d = od; best_k = ok; }
    }

    // all lanes now agree on best_k
    q_table[v * Dc + lane] = cb[best_k * Dc + lane];
    if (lane == 0) {
        idxf_table[v] = (float)best_k;
        d2_table[v]   = best_d;                 // ||codebook[idx] - z||^2
        if (v == 0) out_loss[0] = 0.0f;         // zero the poisoned loss cell
    }
}

// ---------------------------------------------------------------------------
// Kernel 2: gather + loss. One float4 per thread; 16 threads per token.
// grid = Nt*16/256 = 16384 blocks of 256.
// ---------------------------------------------------------------------------
__global__ __launch_bounds__(256) void gather_kernel(
    const int* __restrict__ t, const float* __restrict__ q_table,
    const float* __restrict__ idxf_table, const float* __restrict__ d2_table,
    float* __restrict__ out_q, float* __restrict__ out_idx,
    float* __restrict__ out_loss)
{
    const int g     = blockIdx.x * 256 + threadIdx.x;   // float4 index
    const int token = g >> 4;
    const int part  = g & 15;

    const int tv = t[token];   // 16 lanes share one dword -> HW coalesces

    const float4 q = ((const float4*)q_table)[(tv << 4) + part];  // L2-resident
    ((float4*)out_q)[g] = q;   // fully coalesced 16B/lane store

    float lsum = 0.0f;
    if (part == 0) {
        out_idx[token] = idxf_table[tv];
        lsum = d2_table[tv];
    }

    // block-level loss reduction: wave shuffle then 4-wave LDS combine
    #pragma unroll
    for (int o = 32; o > 0; o >>= 1) lsum += __shfl_xor(lsum, o);
    __shared__ float s_partial[4];
    if ((threadIdx.x & 63) == 0) s_partial[threadIdx.x >> 6] = lsum;
    __syncthreads();
    if (threadIdx.x == 0) {
        const float bs =
            (s_partial[0] + s_partial[1] + s_partial[2] + s_partial[3]) * LOSS_SCALE;
        atomicAdd(out_loss, bs);
    }
}

extern "C" void kernel_launch(void* const* d_in, const int* in_sizes, int n_in,
                              void* d_out, int out_size, void* d_ws, size_t ws_size,
                              hipStream_t stream) {
    const int*   t        = (const int*)d_in[0];     // [B,T,1] int32
    const float* W1       = (const float*)d_in[1];   // [1,H]
    const float* b1       = (const float*)d_in[2];   // [H]
    const float* ln_g     = (const float*)d_in[3];   // [H]
    const float* ln_b     = (const float*)d_in[4];   // [H]
    const float* W2       = (const float*)d_in[5];   // [H,D]
    const float* b2       = (const float*)d_in[6];   // [D]
    const float* codebook = (const float*)d_in[7];   // [K,D]

    float* out      = (float*)d_out;
    float* out_q    = out;                     // Nt*Dc floats
    float* out_idx  = out + (size_t)Nt * Dc;   // Nt floats (idx as float)
    float* out_loss = out_idx + Nt;            // 1 float

    float* ws        = (float*)d_ws;
    float* q_table   = ws;                 // 512*64
    float* idxf_tab  = ws + Kc * Dc;       // 512
    float* d2_tab    = idxf_tab + Kc;      // 512

    precompute_kernel<<<Kc, 64, 0, stream>>>(
        W1, b1, ln_g, ln_b, W2, b2, codebook,
        q_table, idxf_tab, d2_tab, out_loss);

    gather_kernel<<<(Nt * 16) / 256, 256, 0, stream>>>(
        t, q_table, idxf_tab, d2_tab, out_q, out_idx, out_loss);
}

// Round 2
// 110.762 us; speedup vs baseline: 2.7927x; 2.7927x over previous
//
#include <hip/hip_runtime.h>

#define Kc 512
#define Dc 64
#define Hc 64
#define Bc 16
#define Tc 16384
#define Nt (Bc * Tc)              // 262144 tokens
#define LN_EPS 1e-5f
// loss = (1 + 0.25) * mean over N*D elements
#define LOSS_SCALE (1.25f / 16777216.0f)   // 1.25 / (Nt*Dc)

#define GATHER_BLOCKS 4096
#define GATHER_THREADS 256
#define GATHER_ITERS 4            // 4096*256*4 = 4,194,304 float4s = Nt*16

// ---------------------------------------------------------------------------
// Kernel 1: per-t-value table precompute. 512 blocks x 256 threads (4 waves).
// Block v: encoder (first wave) -> z[64] -> 4-wave argmin over 512 codewords
// (each thread 2 rows, float4 loads) -> store q row / idx / d2.
// ---------------------------------------------------------------------------
__global__ __launch_bounds__(256) void precompute_kernel(
    const float* __restrict__ W1, const float* __restrict__ b1,
    const float* __restrict__ ln_g, const float* __restrict__ ln_b,
    const float* __restrict__ W2, const float* __restrict__ b2,
    const float* __restrict__ cb,
    float* __restrict__ q_table, float* __restrict__ idxf_table,
    float* __restrict__ d2_table)
{
    const int v   = blockIdx.x;      // t value, 0..511
    const int tid = threadIdx.x;     // 0..255

    __shared__ float s_h[Hc];
    __shared__ float s_z[Dc];
    __shared__ float s_bd[4];
    __shared__ int   s_bk[4];
    __shared__ int   s_win;
    __shared__ float s_wd;

    // ---- encoder on the first wave only (lane = H index = D index) ----
    if (tid < 64) {
        const int lane = tid;
        const float norm_t = (float)v * (2.0f / (float)(Kc - 1)) - 1.0f;
        float h = norm_t * W1[lane] + b1[lane];

        float s = h;
        #pragma unroll
        for (int o = 32; o > 0; o >>= 1) s += __shfl_xor(s, o);
        const float mu = s * (1.0f / (float)Hc);
        const float d = h - mu;
        float vs = d * d;
        #pragma unroll
        for (int o = 32; o > 0; o >>= 1) vs += __shfl_xor(vs, o);
        const float var = vs * (1.0f / (float)Hc);
        float hn = d * rsqrtf(var + LN_EPS) * ln_g[lane] + ln_b[lane];
        hn = fmaxf(hn, 0.0f);
        s_h[lane] = hn;
        __builtin_amdgcn_s_waitcnt(0);   // LDS write visible within wave
        // z[lane] = sum_h s_h[h] * W2[h][lane] + b2[lane]
        float z = b2[lane];
        #pragma unroll
        for (int hh = 0; hh < Hc; ++hh) z = fmaf(s_h[hh], W2[hh * Dc + lane], z);
        s_z[lane] = z;
    }
    __syncthreads();

    // ---- argmin: thread handles k = tid and tid+256, float4 row loads ----
    const float4* z4 = (const float4*)s_z;   // same-address LDS reads: broadcast
    float best_d = 3.4e38f;
    int best_k = 0;
    #pragma unroll
    for (int half = 0; half < 2; ++half) {
        const int k = tid + half * 256;      // ascending within thread
        const float4* e4 = (const float4*)(cb + k * Dc);
        float dist = 0.0f;
        #pragma unroll
        for (int q = 0; q < 16; ++q) {       // 16 independent 16B loads in flight
            const float4 e = e4[q];
            const float4 zz = z4[q];
            float d0 = zz.x - e.x, d1 = zz.y - e.y, d2 = zz.z - e.z, d3 = zz.w - e.w;
            dist = fmaf(d0, d0, dist); dist = fmaf(d1, d1, dist);
            dist = fmaf(d2, d2, dist); dist = fmaf(d3, d3, dist);
        }
        if (dist < best_d) { best_d = dist; best_k = k; }  // strict < => first idx
    }
    // wave-level lexicographic (d, k) min
    #pragma unroll
    for (int o = 32; o > 0; o >>= 1) {
        const float od = __shfl_xor(best_d, o);
        const int   ok = __shfl_xor(best_k, o);
        if (od < best_d || (od == best_d && ok < best_k)) { best_d = od; best_k = ok; }
    }
    if ((tid & 63) == 0) { s_bd[tid >> 6] = best_d; s_bk[tid >> 6] = best_k; }
    __syncthreads();
    if (tid == 0) {
        float bd = s_bd[0]; int bk = s_bk[0];
        #pragma unroll
        for (int w = 1; w < 4; ++w) {
            const float od = s_bd[w]; const int ok = s_bk[w];
            if (od < bd || (od == bd && ok < bk)) { bd = od; bk = ok; }
        }
        s_win = bk; s_wd = bd;
    }
    __syncthreads();

    if (tid < 64) q_table[v * Dc + tid] = cb[s_win * Dc + tid];
    if (tid == 0) { idxf_table[v] = (float)s_win; d2_table[v] = s_wd; }
}

// ---------------------------------------------------------------------------
// Kernel 2: gather. Grid-stride, 4 float4s/thread. Per-block loss partial to
// ws (NO same-address atomics — that was the 212 us bottleneck).
// ---------------------------------------------------------------------------
__global__ __launch_bounds__(GATHER_THREADS) void gather_kernel(
    const int* __restrict__ t, const float* __restrict__ q_table,
    const float* __restrict__ idxf_table, const float* __restrict__ d2_table,
    float* __restrict__ out_q, float* __restrict__ out_idx,
    float* __restrict__ partials)
{
    const int tid = threadIdx.x;
    const int g0  = blockIdx.x * GATHER_THREADS + tid;
    const int stride = GATHER_BLOCKS * GATHER_THREADS;

    float lsum = 0.0f;
    #pragma unroll
    for (int i = 0; i < GATHER_ITERS; ++i) {
        const int g     = g0 + i * stride;      // float4 index
        const int token = g >> 4;
        const int part  = g & 15;
        const int tv = t[token];                // 16 lanes share one dword
        const float4 q = ((const float4*)q_table)[(tv << 4) + part];  // L2-hit
        ((float4*)out_q)[g] = q;                // coalesced 16B/lane store
        if (part == 0) {
            out_idx[token] = idxf_table[tv];
            lsum += d2_table[tv];
        }
    }

    // block reduction -> one partial per block (no atomics)
    #pragma unroll
    for (int o = 32; o > 0; o >>= 1) lsum += __shfl_xor(lsum, o);
    __shared__ float s_partial[4];
    if ((tid & 63) == 0) s_partial[tid >> 6] = lsum;
    __syncthreads();
    if (tid == 0)
        partials[blockIdx.x] =
            s_partial[0] + s_partial[1] + s_partial[2] + s_partial[3];
}

// ---------------------------------------------------------------------------
// Kernel 3: reduce 4096 partials -> loss. Single block, deterministic.
// ---------------------------------------------------------------------------
__global__ __launch_bounds__(256) void loss_reduce_kernel(
    const float* __restrict__ partials, float* __restrict__ out_loss)
{
    const int tid = threadIdx.x;
    float s = 0.0f;
    #pragma unroll
    for (int i = 0; i < GATHER_BLOCKS / 256; ++i)
        s += partials[i * 256 + tid];
    #pragma unroll
    for (int o = 32; o > 0; o >>= 1) s += __shfl_xor(s, o);
    __shared__ float s_partial[4];
    if ((tid & 63) == 0) s_partial[tid >> 6] = s;
    __syncthreads();
    if (tid == 0)
        out_loss[0] = (s_partial[0] + s_partial[1] + s_partial[2] + s_partial[3])
                      * LOSS_SCALE;
}

extern "C" void kernel_launch(void* const* d_in, const int* in_sizes, int n_in,
                              void* d_out, int out_size, void* d_ws, size_t ws_size,
                              hipStream_t stream) {
    const int*   t        = (const int*)d_in[0];     // [B,T,1] int32
    const float* W1       = (const float*)d_in[1];   // [1,H]
    const float* b1       = (const float*)d_in[2];   // [H]
    const float* ln_g     = (const float*)d_in[3];   // [H]
    const float* ln_b     = (const float*)d_in[4];   // [H]
    const float* W2       = (const float*)d_in[5];   // [H,D]
    const float* b2       = (const float*)d_in[6];   // [D]
    const float* codebook = (const float*)d_in[7];   // [K,D]

    float* out      = (float*)d_out;
    float* out_q    = out;                     // Nt*Dc floats
    float* out_idx  = out + (size_t)Nt * Dc;   // Nt floats (idx as float)
    float* out_loss = out_idx + Nt;            // 1 float

    float* ws        = (float*)d_ws;
    float* q_table   = ws;                        // 512*64
    float* idxf_tab  = ws + Kc * Dc;              // 512
    float* d2_tab    = idxf_tab + Kc;             // 512
    float* partials  = d2_tab + Kc;               // 4096

    precompute_kernel<<<Kc, 256, 0, stream>>>(
        W1, b1, ln_g, ln_b, W2, b2, codebook,
        q_table, idxf_tab, d2_tab);

    gather_kernel<<<GATHER_BLOCKS, GATHER_THREADS, 0, stream>>>(
        t, q_table, idxf_tab, d2_tab, out_q, out_idx, partials);

    loss_reduce_kernel<<<1, 256, 0, stream>>>(partials, out_loss);
}